// Round 10
// baseline (138.025 us; speedup 1.0000x reference)
//
#include <hip/hip_runtime.h>
#include <hip/hip_bf16.h>

typedef unsigned short u16;
typedef unsigned int u32;
typedef __bf16 bf16x8 __attribute__((ext_vector_type(8)));
typedef u16 u16x8 __attribute__((ext_vector_type(8)));
typedef float floatx4 __attribute__((ext_vector_type(4)));

#define T_SEQ 2048
#define HDIM 64
#define NBH 32   // B*H

static __device__ __forceinline__ u16 f2b_rne(float x) {
    union { float f; u32 u; } c; c.f = x;
    u32 u = c.u;
    return (u16)((u + 0x7fffu + ((u >> 16) & 1u)) >> 16);
}
// packed f32x2 -> bf16x2 (RNE), single VALU op (no builtin on gfx950)
static __device__ __forceinline__ u32 cvtpk_bf16(float lo, float hi) {
    u32 r;
    asm("v_cvt_pk_bf16_f32 %0, %1, %2" : "=v"(r) : "v"(lo), "v"(hi));
    return r;
}

// async 16B/lane global->LDS; LDS dest = wave-uniform base + lane*16
#define GLOAD_LDS16(gp, lp)                                                      \
    __builtin_amdgcn_global_load_lds(                                            \
        (const __attribute__((address_space(1))) u32*)(gp),                      \
        (__attribute__((address_space(3))) u32*)(lp), 16, 0, 0)

// counted vmem waits (wait until <= N vmem ops outstanding)
#define WAIT_VM(N) asm volatile("s_waitcnt vmcnt(" #N ")" ::: "memory")

// ---- prepass: K fp32->bf16 flat; V fp32->bf16 transposed [BH,D,T] with
// column permutation pos(k) = tp*32 + qg*8 + u*4 + j  (tp=k>>5, u=(k>>4)&1,
// qg=(k>>2)&3, j=k&3, within each 64-key window) so the 16x16x32 PV B-frag
// (lane quad, elems e=0..7 -> key = tp*32 + (e>>2)*16 + quad*4 + (e&3)) is one
// contiguous 16B region at pos = tp*32 + quad*8. Chunk-preserving. ----
__global__ __launch_bounds__(256) void prep(const float* __restrict__ k,
                                            const float* __restrict__ v,
                                            u16* __restrict__ kb,
                                            u16* __restrict__ vt) {
    __shared__ u16 tile[64][68];
    const int bh = blockIdx.y, t0 = blockIdx.x * 64;
    const int tid = threadIdx.x;

    const float* ksrc = k + ((size_t)bh * T_SEQ + t0) * HDIM;
    u16* kdst = kb + ((size_t)bh * T_SEQ + t0) * HDIM;
#pragma unroll
    for (int p = 0; p < 4; p++) {
        int idx = p * 256 + tid;
        float4 f = ((const float4*)ksrc)[idx];
        ushort4 o;
        o.x = f2b_rne(f.x); o.y = f2b_rne(f.y); o.z = f2b_rne(f.z); o.w = f2b_rne(f.w);
        ((ushort4*)kdst)[idx] = o;
    }

    const float* vsrc = v + ((size_t)bh * T_SEQ + t0) * HDIM;
#pragma unroll
    for (int p = 0; p < 4; p++) {
        int idx = p * 256 + tid;
        int r = idx >> 4, c4 = (idx & 15) * 4;
        float4 f = *(const float4*)(vsrc + r * HDIM + c4);
        tile[c4 + 0][r] = f2b_rne(f.x);
        tile[c4 + 1][r] = f2b_rne(f.y);
        tile[c4 + 2][r] = f2b_rne(f.z);
        tile[c4 + 3][r] = f2b_rne(f.w);
    }
    __syncthreads();
    // 16B stores: pos block pb (8 u16) = keys {tp*32+qg*4+j} u {tp*32+16+qg*4+j}
    u16* dst = vt + (size_t)bh * HDIM * T_SEQ + t0;
#pragma unroll
    for (int p = 0; p < 2; p++) {
        int idx = p * 256 + tid;
        int d = idx >> 3, pb = idx & 7;
        int k0 = (pb >> 2) * 32 + (pb & 3) * 4;
        union { u16x8 v8; ushort4 q[2]; } w;
        w.q[0] = *(ushort4*)&tile[d][k0];
        w.q[1] = *(ushort4*)&tile[d][k0 + 16];
        *(u16x8*)(dst + (size_t)d * T_SEQ + pb * 8) = w.v8;
    }
}

// ---- main kernel ----
// r9 structure frozen (512 blocks x 512 thr / 8 waves, q-tile pair per block,
// wave=(tile,qhalf,khalf) 32qx32k quadrant, pair loop, K ring-4, xcd-local bh)
// EXCEPT: V LDS round-trip ELIMINATED. Per-CU pipe model (r0-r9): LDS ~13us +
// MFMA ~8 + VALU ~11 SUM to the invariant ~39us wall; 7 scheduling
// restructures were null, the only positive delta ever was r2->r3's LDS-read
// cut. So: V frags are loaded DIRECTLY FROM GLOBAL (prep's permutation makes
// each PV B-frag a contiguous 16B region; V is L2-resident: 4bh x 0.5MB/XCD;
// 2x qhalf redundancy = ~25GB/s/CU L2 traffic, trivial). V staging GLOADs
// gone, V ds_reads gone (LDS reads 2.1 -> 1.05 MB/CU), LDS 64->40KB. vf
// issued at top of compute so ~200cyc L2 latency hides under QK+softmax.
// VGPR audit (r8 lesson): ~118 peak < 128 -> 16 waves/CU kept; NO K-carry.
__global__ __launch_bounds__(512, 4) void fattn(const float* __restrict__ q,
                                                const u16* __restrict__ kb,
                                                const u16* __restrict__ vtb,
                                                float* __restrict__ out) {
    __shared__ __align__(16) u16 Kl[4][64 * 64];   // [key][d], XOR slot swizzle, 32KB
    __shared__ __align__(16) floatx4 Xls[4][2][64]; // lsacc exchange, 8KB

    const int id = blockIdx.x;
    const int xcd = id & 7;
    const int u = id >> 3;                         // 0..63
    const int bh = xcd * 4 + (u & 3);              // 4 bh per XCD
    const int s = u >> 2;                          // 0..15
    const int pr = (s & 8) ? (s ^ 7) : s;          // cousin map: CU pairs (s,15-s)
    const int qtHi = 31 - pr, qtLo = pr;

    const int tid = threadIdx.x;
    const int wave = tid >> 6, lane = tid & 63;
    const int l15 = lane & 15, quad = lane >> 4;
    const int tile_sel = wave >> 2;                // 0: hi tile, 1: lo tile
    const int qhalf = (wave >> 1) & 1;             // which 32 q-rows
    const int khalf = wave & 1;                    // which 32 keys
    const int qt = tile_sel ? qtLo : qtHi;
    const int qrow_base = qt * 64 + qhalf * 32;

    const float* qp = q + (size_t)bh * T_SEQ * HDIM;
    const u16* kp = kb + (size_t)bh * T_SEQ * HDIM;
    const u16* vp = vtb + (size_t)bh * HDIM * T_SEQ;

    // K staging: 8 waves cover the 64-row K tile, one 16B GLOAD each
    // (1 vmem/wave/tile). lane covers LDS bytes [wave*1024 + lane*16] = row
    // (wave*8 + (lane>>3)), slot (lane&7). Source picked so LDS slot b at
    // row r holds K block b^(r&7).
    const int srow = wave * 8 + (lane >> 3);
    const int slot = lane & 7;
    const u16* kg0 = kp + srow * HDIM + (slot ^ (srow & 7)) * 8;

    auto stage = [&](int j, int buf) {
        GLOAD_LDS16(kg0 + j * 64 * HDIM, &Kl[buf][wave * 512]);
    };

    // per-lane V fragment source: vf[dt] <- vp + (dt*16+l15)*T_SEQ
    //                                         + j*64 + khalf*32 + quad*8
    const u16* vgf = vp + (size_t)l15 * T_SEQ + khalf * 32 + quad * 8;

    // Q fragments: qf[qb][kc], lane l15 holds Q[row][kc*32+quad*8..+7],
    // pre-scaled by scale*log2(e). Loaded before the pipeline prologue.
    const float SL2E = 0.125f * 1.44269504088896f;
    bf16x8 qf[2][2];
#pragma unroll
    for (int qb = 0; qb < 2; qb++) {
        const float* qrow = qp + (size_t)(qrow_base + qb * 16 + l15) * HDIM;
#pragma unroll
        for (int kc = 0; kc < 2; kc++) {
            const float4* p4 = (const float4*)(qrow + kc * 32 + quad * 8);
            float4 fa = p4[0], fb = p4[1];
            union { bf16x8 v; u16 s[8]; } cv;
            cv.s[0] = f2b_rne(fa.x * SL2E); cv.s[1] = f2b_rne(fa.y * SL2E);
            cv.s[2] = f2b_rne(fa.z * SL2E); cv.s[3] = f2b_rne(fa.w * SL2E);
            cv.s[4] = f2b_rne(fb.x * SL2E); cv.s[5] = f2b_rne(fb.y * SL2E);
            cv.s[6] = f2b_rne(fb.z * SL2E); cv.s[7] = f2b_rne(fb.w * SL2E);
            qf[qb][kc] = cv.v;
        }
    }

    // all-ones bf16 B-frag for MFMA row-sums
    union { u16 h[8]; bf16x8 v; } onesu;
#pragma unroll
    for (int i = 0; i < 8; i++) onesu.h[i] = 0x3F80;
    const bf16x8 ones = onesu.v;

    // prologue: stage the first pair
    stage(0, 0);
    stage(1, 1);

    floatx4 o_acc[2][4];                           // [qb][dt], partial (khalf)
    floatx4 lsacc[2];                              // [qb] partial row-sums
#pragma unroll
    for (int qb = 0; qb < 2; qb++) {
        lsacc[qb] = (floatx4){0.f, 0.f, 0.f, 0.f};
#pragma unroll
        for (int dt = 0; dt < 4; dt++) o_acc[qb][dt] = (floatx4){0.f, 0.f, 0.f, 0.f};
    }

    // one tile's compute; vf from GLOBAL issued first (latency under QK+SM)
    auto compute = [&](int j) {
        const u16* vj = vgf + j * 64;
        bf16x8 vf[4];
#pragma unroll
        for (int dt = 0; dt < 4; dt++)
            vf[dt] = *(const bf16x8*)(vj + (size_t)(dt * 16) * T_SEQ);

        const int cur = j & 3;
        const u16* Kc = Kl[cur];
        bf16x8 kf[2][2];                           // [kc][kb2]
#pragma unroll
        for (int kc = 0; kc < 2; kc++)
#pragma unroll
            for (int kb2 = 0; kb2 < 2; kb2++) {
                int rk = khalf * 32 + kb2 * 16 + l15;
                kf[kc][kb2] = *(const bf16x8*)(Kc + rk * 64 + ((kc * 4 + quad) ^ (rk & 7)) * 8);
            }
        floatx4 sacc[2][2];                        // [kb2][qb]
#pragma unroll
        for (int kb2 = 0; kb2 < 2; kb2++)
#pragma unroll
            for (int qb = 0; qb < 2; qb++) sacc[kb2][qb] = (floatx4){0.f, 0.f, 0.f, 0.f};
        __builtin_amdgcn_s_setprio(1);
#pragma unroll
        for (int kc = 0; kc < 2; kc++)
#pragma unroll
            for (int kb2 = 0; kb2 < 2; kb2++)
#pragma unroll
                for (int qb = 0; qb < 2; qb++)
                    sacc[kb2][qb] = __builtin_amdgcn_mfma_f32_16x16x32_bf16(
                        kf[kc][kb2], qf[qb][kc], sacc[kb2][qb], 0, 0, 0);
        __builtin_amdgcn_s_setprio(0);

        // P^T = exp2(S^T); causal mask on diagonal tile; pack via cvt_pk into
        // PV A-frags: elem e = kb2*4+rg <-> key khalf*32 + kb2*16 + quad*4 + rg
        union { bf16x8 v; u32 w[4]; } pk[2];
        if (j == qt) {
            const int key0 = khalf * 32 + quad * 4;
#pragma unroll
            for (int qb = 0; qb < 2; qb++) {
                const int gq = qhalf * 32 + qb * 16 + l15;
#pragma unroll
                for (int kb2 = 0; kb2 < 2; kb2++) {
                    float e0 = __builtin_amdgcn_exp2f(sacc[kb2][qb][0]);
                    float e1 = __builtin_amdgcn_exp2f(sacc[kb2][qb][1]);
                    float e2 = __builtin_amdgcn_exp2f(sacc[kb2][qb][2]);
                    float e3 = __builtin_amdgcn_exp2f(sacc[kb2][qb][3]);
                    int kbase = key0 + kb2 * 16;
                    if (kbase + 0 > gq) e0 = 0.f;
                    if (kbase + 1 > gq) e1 = 0.f;
                    if (kbase + 2 > gq) e2 = 0.f;
                    if (kbase + 3 > gq) e3 = 0.f;
                    pk[qb].w[kb2 * 2 + 0] = cvtpk_bf16(e0, e1);
                    pk[qb].w[kb2 * 2 + 1] = cvtpk_bf16(e2, e3);
                }
            }
        } else {
#pragma unroll
            for (int qb = 0; qb < 2; qb++)
#pragma unroll
                for (int kb2 = 0; kb2 < 2; kb2++) {
                    float e0 = __builtin_amdgcn_exp2f(sacc[kb2][qb][0]);
                    float e1 = __builtin_amdgcn_exp2f(sacc[kb2][qb][1]);
                    float e2 = __builtin_amdgcn_exp2f(sacc[kb2][qb][2]);
                    float e3 = __builtin_amdgcn_exp2f(sacc[kb2][qb][3]);
                    pk[qb].w[kb2 * 2 + 0] = cvtpk_bf16(e0, e1);
                    pk[qb].w[kb2 * 2 + 1] = cvtpk_bf16(e2, e3);
                }
        }

        // O_partial += P . V (8 MFMA) ; row-sums += P . ones (2 MFMA)
        __builtin_amdgcn_s_setprio(1);
#pragma unroll
        for (int dt = 0; dt < 4; dt++)
#pragma unroll
            for (int qb = 0; qb < 2; qb++)
                o_acc[qb][dt] = __builtin_amdgcn_mfma_f32_16x16x32_bf16(
                    pk[qb].v, vf[dt], o_acc[qb][dt], 0, 0, 0);
        lsacc[0] = __builtin_amdgcn_mfma_f32_16x16x32_bf16(pk[0].v, ones, lsacc[0], 0, 0, 0);
        lsacc[1] = __builtin_amdgcn_mfma_f32_16x16x32_bf16(pk[1].v, ones, lsacc[1], 0, 0, 0);
        __builtin_amdgcn_s_setprio(0);
    };

    // pair loop: one wait+barrier per 2 tiles (K staging only)
    for (int j = 0; j <= qtHi; j += 2) {
        WAIT_VM(0);                                // retire K tiles {j, j+1}
        __builtin_amdgcn_s_barrier();              // all waves' pair in LDS
        if (j + 2 <= qtHi) stage(j + 2, (j + 2) & 3);  // into free ring slots
        if (j + 3 <= qtHi) stage(j + 3, (j + 3) & 3);

        if (j <= qt) compute(j);                   // wave-uniform guards
        if (j + 1 <= qtHi && j + 1 <= qt) compute(j + 1);
    }

    // ---- epilogue: khalf pair-reduce via LDS, normalize, store ----
    // lsacc[qb][rg] = partial row-sum for q = qrow_base + qb*16 + quad*4 + rg
    // (identical across l15) -- exactly o_acc's row indexing. Per wave-pair
    // region: 8 o-planes in Kl (8KB each, 4 regions = 32KB) + lsacc in Xls.
    __syncthreads();                               // main-loop LDS use complete
    const int r = wave >> 1;                       // pair region 0..3
    floatx4* xo = (floatx4*)((char*)&Kl[0][0] + r * 8192);
    if (khalf == 0) {
#pragma unroll
        for (int qb = 0; qb < 2; qb++) {
#pragma unroll
            for (int dt = 0; dt < 4; dt++) xo[(qb * 4 + dt) * 64 + lane] = o_acc[qb][dt];
            Xls[r][qb][lane] = lsacc[qb];
        }
    }
    __syncthreads();
    if (khalf == 1) {
        float* op = out + (size_t)bh * T_SEQ * HDIM;
#pragma unroll
        for (int qb = 0; qb < 2; qb++) {
#pragma unroll
            for (int dt = 0; dt < 4; dt++) o_acc[qb][dt] += xo[(qb * 4 + dt) * 64 + lane];
            lsacc[qb] += Xls[r][qb][lane];
#pragma unroll
            for (int rg = 0; rg < 4; rg++) {
                float inv = 1.0f / lsacc[qb][rg];
                size_t row = (size_t)(qrow_base + qb * 16 + quad * 4 + rg) * HDIM;
#pragma unroll
                for (int dt = 0; dt < 4; dt++)
                    op[row + dt * 16 + l15] = o_acc[qb][dt][rg] * inv;
            }
        }
    }
}

extern "C" void kernel_launch(void* const* d_in, const int* in_sizes, int n_in,
                              void* d_out, int out_size, void* d_ws, size_t ws_size,
                              hipStream_t stream) {
    const float* q = (const float*)d_in[0];
    const float* k = (const float*)d_in[1];
    const float* v = (const float*)d_in[2];
    float* out = (float*)d_out;

    u16* kb = (u16*)d_ws;                               // 8 MB bf16 K
    u16* vt = kb + (size_t)NBH * T_SEQ * HDIM;          // 8 MB bf16 V^T (permuted)

    prep<<<dim3(T_SEQ / 64, NBH), 256, 0, stream>>>(k, v, kb, vt);
    fattn<<<dim3(512), 512, 0, stream>>>(q, kb, vt, out);
}

// Round 11
// 137.377 us; speedup vs baseline: 1.0047x; 1.0047x over previous
//
#include <hip/hip_runtime.h>
#include <hip/hip_bf16.h>

typedef unsigned short u16;
typedef unsigned int u32;
typedef __bf16 bf16x8 __attribute__((ext_vector_type(8)));
typedef u16 u16x8 __attribute__((ext_vector_type(8)));
typedef float floatx4 __attribute__((ext_vector_type(4)));

#define T_SEQ 2048
#define HDIM 64
#define NBH 32   // B*H

static __device__ __forceinline__ u16 f2b_rne(float x) {
    union { float f; u32 u; } c; c.f = x;
    u32 u = c.u;
    return (u16)((u + 0x7fffu + ((u >> 16) & 1u)) >> 16);
}
// packed f32x2 -> bf16x2 (RNE), single VALU op (no builtin on gfx950)
static __device__ __forceinline__ u32 cvtpk_bf16(float lo, float hi) {
    u32 r;
    asm("v_cvt_pk_bf16_f32 %0, %1, %2" : "=v"(r) : "v"(lo), "v"(hi));
    return r;
}

// async 16B/lane global->LDS; LDS dest = wave-uniform base + lane*16
#define GLOAD_LDS16(gp, lp)                                                      \
    __builtin_amdgcn_global_load_lds(                                            \
        (const __attribute__((address_space(1))) u32*)(gp),                      \
        (__attribute__((address_space(3))) u32*)(lp), 16, 0, 0)

// counted vmem waits (wait until <= N vmem ops outstanding)
#define WAIT_VM(N) asm volatile("s_waitcnt vmcnt(" #N ")" ::: "memory")

// ---- prepass: K fp32->bf16 flat; V fp32->bf16 transposed [BH,D,T] with
// column permutation pos(k) = tp*32 + qg*8 + u*4 + j  (tp=k>>5, u=(k>>4)&1,
// qg=(k>>2)&3, j=k&3, within each 64-key window) so the 16x16x32 PV B-frag
// (lane quad, elems e=0..7 -> key = tp*32 + (e>>2)*16 + quad*4 + (e&3)) is one
// contiguous 16B region at pos = tp*32 + quad*8. Chunk-preserving. ----
__global__ __launch_bounds__(256) void prep(const float* __restrict__ k,
                                            const float* __restrict__ v,
                                            u16* __restrict__ kb,
                                            u16* __restrict__ vt) {
    __shared__ u16 tile[64][68];
    const int bh = blockIdx.y, t0 = blockIdx.x * 64;
    const int tid = threadIdx.x;

    const float* ksrc = k + ((size_t)bh * T_SEQ + t0) * HDIM;
    u16* kdst = kb + ((size_t)bh * T_SEQ + t0) * HDIM;
#pragma unroll
    for (int p = 0; p < 4; p++) {
        int idx = p * 256 + tid;
        float4 f = ((const float4*)ksrc)[idx];
        ushort4 o;
        o.x = f2b_rne(f.x); o.y = f2b_rne(f.y); o.z = f2b_rne(f.z); o.w = f2b_rne(f.w);
        ((ushort4*)kdst)[idx] = o;
    }

    const float* vsrc = v + ((size_t)bh * T_SEQ + t0) * HDIM;
#pragma unroll
    for (int p = 0; p < 4; p++) {
        int idx = p * 256 + tid;
        int r = idx >> 4, c4 = (idx & 15) * 4;
        float4 f = *(const float4*)(vsrc + r * HDIM + c4);
        tile[c4 + 0][r] = f2b_rne(f.x);
        tile[c4 + 1][r] = f2b_rne(f.y);
        tile[c4 + 2][r] = f2b_rne(f.z);
        tile[c4 + 3][r] = f2b_rne(f.w);
    }
    __syncthreads();
    // 16B stores: pos block pb (8 u16) = keys {tp*32+qg*4+j} u {tp*32+16+qg*4+j}
    u16* dst = vt + (size_t)bh * HDIM * T_SEQ + t0;
#pragma unroll
    for (int p = 0; p < 2; p++) {
        int idx = p * 256 + tid;
        int d = idx >> 3, pb = idx & 7;
        int k0 = (pb >> 2) * 32 + (pb & 3) * 4;
        union { u16x8 v8; ushort4 q[2]; } w;
        w.q[0] = *(ushort4*)&tile[d][k0];
        w.q[1] = *(ushort4*)&tile[d][k0 + 16];
        *(u16x8*)(dst + (size_t)d * T_SEQ + pb * 8) = w.v8;
    }
}

// ---- main kernel ----
// r9 structure frozen (512 blocks x 512 thr / 8 waves, q-tile pair per block,
// wave=(tile,qhalf,khalf) 32qx32k quadrant, pair loop, K ring-4, xcd-local bh)
// with V DIRECT FROM GLOBAL, double-buffered, ISSUE-ORDER-AWARE:
// r10 proved vmcnt retires IN ISSUE ORDER, so its vf-after-staging order made
// every PV wait = vmcnt(0) -> drained the K prefetch each compute (+15us).
// Fix: per pair issue vfA(j) x4, vfB(j+1) x4 FIRST, then stage(j+2),(j+3).
// compute(j) PV waits vmcnt(6) (retires vfA only), compute(j+1) waits
// vmcnt(2) (retires vfB) -- K prefetch stays in flight across the whole pair.
// vfB gets ~1000cyc cover, vfA ~350cyc vs ~200cyc L2 latency (V L2-resident:
// 4bh x 0.5MB/XCD). LDS: V reads/writes gone (reads 2.1->1.05MB/CU), 40KB.
// VGPR audit: r10=60 + vfB persistent 16 + vfA 16 ~= 92 < 128 -> 16 waves/CU.
__global__ __launch_bounds__(512, 4) void fattn(const float* __restrict__ q,
                                                const u16* __restrict__ kb,
                                                const u16* __restrict__ vtb,
                                                float* __restrict__ out) {
    __shared__ __align__(16) u16 Kl[4][64 * 64];   // [key][d], XOR slot swizzle, 32KB
    __shared__ __align__(16) floatx4 Xls[4][2][64]; // lsacc exchange, 8KB

    const int id = blockIdx.x;
    const int xcd = id & 7;
    const int u = id >> 3;                         // 0..63
    const int bh = xcd * 4 + (u & 3);              // 4 bh per XCD
    const int s = u >> 2;                          // 0..15
    const int pr = (s & 8) ? (s ^ 7) : s;          // cousin map: CU pairs (s,15-s)
    const int qtHi = 31 - pr, qtLo = pr;

    const int tid = threadIdx.x;
    const int wave = tid >> 6, lane = tid & 63;
    const int l15 = lane & 15, quad = lane >> 4;
    const int tile_sel = wave >> 2;                // 0: hi tile, 1: lo tile
    const int qhalf = (wave >> 1) & 1;             // which 32 q-rows
    const int khalf = wave & 1;                    // which 32 keys
    const int qt = tile_sel ? qtLo : qtHi;
    const int qrow_base = qt * 64 + qhalf * 32;

    const float* qp = q + (size_t)bh * T_SEQ * HDIM;
    const u16* kp = kb + (size_t)bh * T_SEQ * HDIM;
    const u16* vp = vtb + (size_t)bh * HDIM * T_SEQ;

    // K staging: 8 waves cover the 64-row K tile, one 16B GLOAD each
    // (1 vmem/wave/tile). lane covers LDS bytes [wave*1024 + lane*16] = row
    // (wave*8 + (lane>>3)), slot (lane&7). Source picked so LDS slot b at
    // row r holds K block b^(r&7).
    const int srow = wave * 8 + (lane >> 3);
    const int slot = lane & 7;
    const u16* kg0 = kp + srow * HDIM + (slot ^ (srow & 7)) * 8;

    auto stage = [&](int j, int buf) {
        GLOAD_LDS16(kg0 + j * 64 * HDIM, &Kl[buf][wave * 512]);
    };

    // per-lane V fragment source: vf[dt] <- vp + (dt*16+l15)*T_SEQ
    //                                         + j*64 + khalf*32 + quad*8
    const u16* vgf = vp + (size_t)l15 * T_SEQ + khalf * 32 + quad * 8;

    // Q fragments: qf[qb][kc], lane l15 holds Q[row][kc*32+quad*8..+7],
    // pre-scaled by scale*log2(e). Loaded before the pipeline prologue.
    const float SL2E = 0.125f * 1.44269504088896f;
    bf16x8 qf[2][2];
#pragma unroll
    for (int qb = 0; qb < 2; qb++) {
        const float* qrow = qp + (size_t)(qrow_base + qb * 16 + l15) * HDIM;
#pragma unroll
        for (int kc = 0; kc < 2; kc++) {
            const float4* p4 = (const float4*)(qrow + kc * 32 + quad * 8);
            float4 fa = p4[0], fb = p4[1];
            union { bf16x8 v; u16 s[8]; } cv;
            cv.s[0] = f2b_rne(fa.x * SL2E); cv.s[1] = f2b_rne(fa.y * SL2E);
            cv.s[2] = f2b_rne(fa.z * SL2E); cv.s[3] = f2b_rne(fa.w * SL2E);
            cv.s[4] = f2b_rne(fb.x * SL2E); cv.s[5] = f2b_rne(fb.y * SL2E);
            cv.s[6] = f2b_rne(fb.z * SL2E); cv.s[7] = f2b_rne(fb.w * SL2E);
            qf[qb][kc] = cv.v;
        }
    }

    // all-ones bf16 B-frag for MFMA row-sums
    union { u16 h[8]; bf16x8 v; } onesu;
#pragma unroll
    for (int i = 0; i < 8; i++) onesu.h[i] = 0x3F80;
    const bf16x8 ones = onesu.v;

    // prologue: stage the first pair of K tiles
    stage(0, 0);
    stage(1, 1);

    floatx4 o_acc[2][4];                           // [qb][dt], partial (khalf)
    floatx4 lsacc[2];                              // [qb] partial row-sums
#pragma unroll
    for (int qb = 0; qb < 2; qb++) {
        lsacc[qb] = (floatx4){0.f, 0.f, 0.f, 0.f};
#pragma unroll
        for (int dt = 0; dt < 4; dt++) o_acc[qb][dt] = (floatx4){0.f, 0.f, 0.f, 0.f};
    }

    // one tile's compute; vf passed in (already issued, in-order-retirable)
    auto compute = [&](int j, bf16x8 (&vf)[4]) {
        const int cur = j & 3;
        const u16* Kc = Kl[cur];
        bf16x8 kf[2][2];                           // [kc][kb2]
#pragma unroll
        for (int kc = 0; kc < 2; kc++)
#pragma unroll
            for (int kb2 = 0; kb2 < 2; kb2++) {
                int rk = khalf * 32 + kb2 * 16 + l15;
                kf[kc][kb2] = *(const bf16x8*)(Kc + rk * 64 + ((kc * 4 + quad) ^ (rk & 7)) * 8);
            }
        floatx4 sacc[2][2];                        // [kb2][qb]
#pragma unroll
        for (int kb2 = 0; kb2 < 2; kb2++)
#pragma unroll
            for (int qb = 0; qb < 2; qb++) sacc[kb2][qb] = (floatx4){0.f, 0.f, 0.f, 0.f};
        __builtin_amdgcn_s_setprio(1);
#pragma unroll
        for (int kc = 0; kc < 2; kc++)
#pragma unroll
            for (int kb2 = 0; kb2 < 2; kb2++)
#pragma unroll
                for (int qb = 0; qb < 2; qb++)
                    sacc[kb2][qb] = __builtin_amdgcn_mfma_f32_16x16x32_bf16(
                        kf[kc][kb2], qf[qb][kc], sacc[kb2][qb], 0, 0, 0);
        __builtin_amdgcn_s_setprio(0);

        // P^T = exp2(S^T); causal mask on diagonal tile; pack via cvt_pk into
        // PV A-frags: elem e = kb2*4+rg <-> key khalf*32 + kb2*16 + quad*4 + rg
        union { bf16x8 v; u32 w[4]; } pk[2];
        if (j == qt) {
            const int key0 = khalf * 32 + quad * 4;
#pragma unroll
            for (int qb = 0; qb < 2; qb++) {
                const int gq = qhalf * 32 + qb * 16 + l15;
#pragma unroll
                for (int kb2 = 0; kb2 < 2; kb2++) {
                    float e0 = __builtin_amdgcn_exp2f(sacc[kb2][qb][0]);
                    float e1 = __builtin_amdgcn_exp2f(sacc[kb2][qb][1]);
                    float e2 = __builtin_amdgcn_exp2f(sacc[kb2][qb][2]);
                    float e3 = __builtin_amdgcn_exp2f(sacc[kb2][qb][3]);
                    int kbase = key0 + kb2 * 16;
                    if (kbase + 0 > gq) e0 = 0.f;
                    if (kbase + 1 > gq) e1 = 0.f;
                    if (kbase + 2 > gq) e2 = 0.f;
                    if (kbase + 3 > gq) e3 = 0.f;
                    pk[qb].w[kb2 * 2 + 0] = cvtpk_bf16(e0, e1);
                    pk[qb].w[kb2 * 2 + 1] = cvtpk_bf16(e2, e3);
                }
            }
        } else {
#pragma unroll
            for (int qb = 0; qb < 2; qb++)
#pragma unroll
                for (int kb2 = 0; kb2 < 2; kb2++) {
                    float e0 = __builtin_amdgcn_exp2f(sacc[kb2][qb][0]);
                    float e1 = __builtin_amdgcn_exp2f(sacc[kb2][qb][1]);
                    float e2 = __builtin_amdgcn_exp2f(sacc[kb2][qb][2]);
                    float e3 = __builtin_amdgcn_exp2f(sacc[kb2][qb][3]);
                    pk[qb].w[kb2 * 2 + 0] = cvtpk_bf16(e0, e1);
                    pk[qb].w[kb2 * 2 + 1] = cvtpk_bf16(e2, e3);
                }
        }

        // O_partial += P . V (8 MFMA) ; row-sums += P . ones (2 MFMA)
        __builtin_amdgcn_s_setprio(1);
#pragma unroll
        for (int dt = 0; dt < 4; dt++)
#pragma unroll
            for (int qb = 0; qb < 2; qb++)
                o_acc[qb][dt] = __builtin_amdgcn_mfma_f32_16x16x32_bf16(
                    pk[qb].v, vf[dt], o_acc[qb][dt], 0, 0, 0);
        lsacc[0] = __builtin_amdgcn_mfma_f32_16x16x32_bf16(pk[0].v, ones, lsacc[0], 0, 0, 0);
        lsacc[1] = __builtin_amdgcn_mfma_f32_16x16x32_bf16(pk[1].v, ones, lsacc[1], 0, 0, 0);
        __builtin_amdgcn_s_setprio(0);
    };

    // pair loop: one wait+barrier per 2 tiles; vmem ISSUE ORDER per pair:
    // [vfA x4, vfB x4, stageK x2] -> PV(j) waits vmcnt(6), PV(j+1) vmcnt(2),
    // K prefetch retired only by next pair's WAIT_VM(0).
    for (int j = 0; j <= qtHi; j += 2) {
        WAIT_VM(0);                                // retire K tiles {j, j+1}
        __builtin_amdgcn_s_barrier();              // all waves' pair in LDS

        bf16x8 vfA[4], vfB[4];
        const bool doA = (j <= qt);                // wave-uniform
        const bool doB = (j + 1 <= qt);
        if (doA) {
            const u16* vj = vgf + j * 64;
#pragma unroll
            for (int dt = 0; dt < 4; dt++)
                vfA[dt] = *(const bf16x8*)(vj + (size_t)(dt * 16) * T_SEQ);
        }
        if (doB) {
            const u16* vj = vgf + (j + 1) * 64;
#pragma unroll
            for (int dt = 0; dt < 4; dt++)
                vfB[dt] = *(const bf16x8*)(vj + (size_t)(dt * 16) * T_SEQ);
        }
        if (j + 2 <= qtHi) stage(j + 2, (j + 2) & 3);  // into free ring slots
        if (j + 3 <= qtHi) stage(j + 3, (j + 3) & 3);

        if (doA) compute(j, vfA);
        if (doB) compute(j + 1, vfB);
    }

    // ---- epilogue: khalf pair-reduce via LDS, normalize, store ----
    // lsacc[qb][rg] = partial row-sum for q = qrow_base + qb*16 + quad*4 + rg
    // (identical across l15) -- exactly o_acc's row indexing. Per wave-pair
    // region: 8 o-planes in Kl (8KB each, 4 regions = 32KB) + lsacc in Xls.
    __syncthreads();                               // main-loop LDS use complete
    const int r = wave >> 1;                       // pair region 0..3
    floatx4* xo = (floatx4*)((char*)&Kl[0][0] + r * 8192);
    if (khalf == 0) {
#pragma unroll
        for (int qb = 0; qb < 2; qb++) {
#pragma unroll
            for (int dt = 0; dt < 4; dt++) xo[(qb * 4 + dt) * 64 + lane] = o_acc[qb][dt];
            Xls[r][qb][lane] = lsacc[qb];
        }
    }
    __syncthreads();
    if (khalf == 1) {
        float* op = out + (size_t)bh * T_SEQ * HDIM;
#pragma unroll
        for (int qb = 0; qb < 2; qb++) {
#pragma unroll
            for (int dt = 0; dt < 4; dt++) o_acc[qb][dt] += xo[(qb * 4 + dt) * 64 + lane];
            lsacc[qb] += Xls[r][qb][lane];
#pragma unroll
            for (int rg = 0; rg < 4; rg++) {
                float inv = 1.0f / lsacc[qb][rg];
                size_t row = (size_t)(qrow_base + qb * 16 + quad * 4 + rg) * HDIM;
#pragma unroll
                for (int dt = 0; dt < 4; dt++)
                    op[row + dt * 16 + l15] = o_acc[qb][dt][rg] * inv;
            }
        }
    }
}

extern "C" void kernel_launch(void* const* d_in, const int* in_sizes, int n_in,
                              void* d_out, int out_size, void* d_ws, size_t ws_size,
                              hipStream_t stream) {
    const float* q = (const float*)d_in[0];
    const float* k = (const float*)d_in[1];
    const float* v = (const float*)d_in[2];
    float* out = (float*)d_out;

    u16* kb = (u16*)d_ws;                               // 8 MB bf16 K
    u16* vt = kb + (size_t)NBH * T_SEQ * HDIM;          // 8 MB bf16 V^T (permuted)

    prep<<<dim3(T_SEQ / 64, NBH), 256, 0, stream>>>(k, v, kb, vt);
    fattn<<<dim3(512), 512, 0, stream>>>(q, kb, vt, out);
}

// Round 12
// 119.105 us; speedup vs baseline: 1.1589x; 1.1534x over previous
//
#include <hip/hip_runtime.h>
#include <hip/hip_bf16.h>

typedef unsigned short u16;
typedef unsigned int u32;
typedef __bf16 bf16x8 __attribute__((ext_vector_type(8)));
typedef u16 u16x8 __attribute__((ext_vector_type(8)));
typedef float floatx4 __attribute__((ext_vector_type(4)));

#define T_SEQ 2048
#define HDIM 64
#define NBH 32   // B*H

static __device__ __forceinline__ u16 f2b_rne(float x) {
    union { float f; u32 u; } c; c.f = x;
    u32 u = c.u;
    return (u16)((u + 0x7fffu + ((u >> 16) & 1u)) >> 16);
}
// packed f32x2 -> bf16x2 (RNE), single VALU op (no builtin on gfx950)
static __device__ __forceinline__ u32 cvtpk_bf16(float lo, float hi) {
    u32 r;
    asm("v_cvt_pk_bf16_f32 %0, %1, %2" : "=v"(r) : "v"(lo), "v"(hi));
    return r;
}

// async 16B/lane global->LDS; LDS dest = wave-uniform base + lane*16
#define GLOAD_LDS16(gp, lp)                                                      \
    __builtin_amdgcn_global_load_lds(                                            \
        (const __attribute__((address_space(1))) u32*)(gp),                      \
        (__attribute__((address_space(3))) u32*)(lp), 16, 0, 0)

// counted vmem waits (wait until <= N vmem ops outstanding)
#define WAIT_VM(N) asm volatile("s_waitcnt vmcnt(" #N ")" ::: "memory")

// ---- prepass (REBUILT for latency/phase overlap; e2e decomposition across
// r0-r11 shows prep ~37us, 2.5x its ~14us BW floor -- as big as fattn):
// 2048 blocks x 256 thr, each a 32-KEY SLAB (the V permutation is 32-chunk-
// preserving, so slabs split cleanly: global pos = t0 + pos32). V loads issue
// FIRST; K stream conversion overlaps their latency; ONE barrier; V goes
// straight to a permuted-transposed LDS tile t2[pos][d] (single pass, aligned
// ushort4 writes); all f32->bf16 via v_cvt_pk (2 ops/float4, ~6x less VALU).
// pos32(r) = ((r>>2)&3)*8 + ((r>>4)&1)*4 + (r&3) -- same permutation as
// before: the 16x16x32 PV B-frag is a contiguous 16B region of V^T. ----
__global__ __launch_bounds__(256) void prep(const float* __restrict__ k,
                                            const float* __restrict__ v,
                                            u16* __restrict__ kb,
                                            u16* __restrict__ vt) {
    __shared__ __align__(16) u16 t2[32][72];       // [pos32][d], pad->72
    const int bh = blockIdx.y, t0 = blockIdx.x * 32;
    const int tid = threadIdx.x;

    // V loads first: 32 rows x 64 d = 512 float4
    const float* vsrc = v + ((size_t)bh * T_SEQ + t0) * HDIM;
    float4 vf[2];
#pragma unroll
    for (int p = 0; p < 2; p++) vf[p] = ((const float4*)vsrc)[p * 256 + tid];

    // K streaming conversion (independent work hides V load latency)
    const float* ksrc = k + ((size_t)bh * T_SEQ + t0) * HDIM;
    u16* kdst = kb + ((size_t)bh * T_SEQ + t0) * HDIM;
#pragma unroll
    for (int p = 0; p < 2; p++) {
        float4 f = ((const float4*)ksrc)[p * 256 + tid];
        union { u32 w[2]; ushort4 s; } o;
        o.w[0] = cvtpk_bf16(f.x, f.y);
        o.w[1] = cvtpk_bf16(f.z, f.w);
        ((ushort4*)kdst)[p * 256 + tid] = o.s;
    }

    // V -> LDS, permuted-transposed in one pass (aligned 8B writes)
#pragma unroll
    for (int p = 0; p < 2; p++) {
        int idx = p * 256 + tid;
        int r = idx >> 4, c4 = (idx & 15) * 4;
        int pos = ((r >> 2) & 3) * 8 + ((r >> 4) & 1) * 4 + (r & 3);
        union { u32 w[2]; ushort4 s; } o;
        o.w[0] = cvtpk_bf16(vf[p].x, vf[p].y);
        o.w[1] = cvtpk_bf16(vf[p].z, vf[p].w);
        *(ushort4*)&t2[pos][c4] = o.s;
    }
    __syncthreads();

    // V^T store: 64 d x 32 pos, one 16B store per thread
    u16* dst = vt + (size_t)bh * HDIM * T_SEQ + t0;
    {
        int d = tid >> 2, pb = tid & 3;
        union { u16x8 v8; u16 h[8]; } w;
#pragma unroll
        for (int i = 0; i < 8; i++) w.h[i] = t2[pb * 8 + i][d];
        *(u16x8*)(dst + (size_t)d * T_SEQ + pb * 8) = w.v8;
    }
}

// ---- main kernel: EXACT r9 (best measured, e2e 119.56; fattn ~39us).
// 512 blocks x 512 thr / 8 waves, block = q-tile pair (qtHi=31-pr, qtLo=pr),
// wave=(tile,qhalf,khalf) 32qx32k quadrant, K+V ring-4 LDS, pair loop (one
// vmcnt(0)+barrier per 2 tiles), xcd-local bh, cvt_pk P-pack. ----
__global__ __launch_bounds__(512, 4) void fattn(const float* __restrict__ q,
                                                const u16* __restrict__ kb,
                                                const u16* __restrict__ vtb,
                                                float* __restrict__ out) {
    __shared__ __align__(16) u16 Kl[4][64 * 64];   // [key][d], XOR slot swizzle
    __shared__ __align__(16) u16 Vl[4][64 * 64];   // [d][perm-key], +d slot swizzle

    const int id = blockIdx.x;
    const int xcd = id & 7;
    const int u = id >> 3;                         // 0..63
    const int bh = xcd * 4 + (u & 3);              // 4 bh per XCD
    const int s = u >> 2;                          // 0..15
    const int pr = (s & 8) ? (s ^ 7) : s;          // cousin map: CU pairs (s,15-s)
    const int qtHi = 31 - pr, qtLo = pr;

    const int tid = threadIdx.x;
    const int wave = tid >> 6, lane = tid & 63;
    const int l15 = lane & 15, quad = lane >> 4;
    const int tile_sel = wave >> 2;                // 0: hi tile, 1: lo tile
    const int qhalf = (wave >> 1) & 1;             // which 32 q-rows
    const int khalf = wave & 1;                    // which 32 keys
    const int qt = tile_sel ? qtLo : qtHi;
    const int qrow_base = qt * 64 + qhalf * 32;

    const float* qp = q + (size_t)bh * T_SEQ * HDIM;
    const u16* kp = kb + (size_t)bh * T_SEQ * HDIM;
    const u16* vp = vtb + (size_t)bh * HDIM * T_SEQ;

    // staging: 8 waves cover the full 64-row K tile and 64-row V^T tile,
    // one 16B GLOAD each (2 vmem/wave/tile). lane covers LDS bytes
    // [wave*1024 + lane*16] = row (wave*8 + (lane>>3)), slot (lane&7).
    // Source picked so LDS slot b at row r holds: K block b^(r&7);
    // V perm-slot (b-r)&7.
    const int srow = wave * 8 + (lane >> 3);
    const int slot = lane & 7;
    const u16* kg0 = kp + srow * HDIM + (slot ^ (srow & 7)) * 8;
    const u16* vg0 = vp + (size_t)srow * T_SEQ + ((slot - srow) & 7) * 8;

    auto stage = [&](int j, int buf) {
        GLOAD_LDS16(kg0 + j * 64 * HDIM, &Kl[buf][wave * 512]);
        GLOAD_LDS16(vg0 + j * 64, &Vl[buf][wave * 512]);
    };

    // Q fragments: qf[qb][kc], lane l15 holds Q[row][kc*32+quad*8..+7],
    // pre-scaled by scale*log2(e). Loaded before the pipeline prologue.
    const float SL2E = 0.125f * 1.44269504088896f;
    bf16x8 qf[2][2];
#pragma unroll
    for (int qb = 0; qb < 2; qb++) {
        const float* qrow = qp + (size_t)(qrow_base + qb * 16 + l15) * HDIM;
#pragma unroll
        for (int kc = 0; kc < 2; kc++) {
            const float4* p4 = (const float4*)(qrow + kc * 32 + quad * 8);
            float4 fa = p4[0], fb = p4[1];
            union { bf16x8 v; u16 s[8]; } cv;
            cv.s[0] = f2b_rne(fa.x * SL2E); cv.s[1] = f2b_rne(fa.y * SL2E);
            cv.s[2] = f2b_rne(fa.z * SL2E); cv.s[3] = f2b_rne(fa.w * SL2E);
            cv.s[4] = f2b_rne(fb.x * SL2E); cv.s[5] = f2b_rne(fb.y * SL2E);
            cv.s[6] = f2b_rne(fb.z * SL2E); cv.s[7] = f2b_rne(fb.w * SL2E);
            qf[qb][kc] = cv.v;
        }
    }

    // all-ones bf16 B-frag for MFMA row-sums
    union { u16 h[8]; bf16x8 v; } onesu;
#pragma unroll
    for (int i = 0; i < 8; i++) onesu.h[i] = 0x3F80;
    const bf16x8 ones = onesu.v;

    // prologue: stage the first pair
    stage(0, 0);
    stage(1, 1);

    floatx4 o_acc[2][4];                           // [qb][dt], partial (khalf)
    floatx4 lsacc[2];                              // [qb] partial row-sums
#pragma unroll
    for (int qb = 0; qb < 2; qb++) {
        lsacc[qb] = (floatx4){0.f, 0.f, 0.f, 0.f};
#pragma unroll
        for (int dt = 0; dt < 4; dt++) o_acc[qb][dt] = (floatx4){0.f, 0.f, 0.f, 0.f};
    }

    // one tile's compute, register-minimal phase order
    auto compute = [&](int j) {
        const int cur = j & 3;
        const u16* Kc = Kl[cur];
        bf16x8 kf[2][2];                           // [kc][kb2]
#pragma unroll
        for (int kc = 0; kc < 2; kc++)
#pragma unroll
            for (int kb2 = 0; kb2 < 2; kb2++) {
                int rk = khalf * 32 + kb2 * 16 + l15;
                kf[kc][kb2] = *(const bf16x8*)(Kc + rk * 64 + ((kc * 4 + quad) ^ (rk & 7)) * 8);
            }
        floatx4 sacc[2][2];                        // [kb2][qb]
#pragma unroll
        for (int kb2 = 0; kb2 < 2; kb2++)
#pragma unroll
            for (int qb = 0; qb < 2; qb++) sacc[kb2][qb] = (floatx4){0.f, 0.f, 0.f, 0.f};
        __builtin_amdgcn_s_setprio(1);
#pragma unroll
        for (int kc = 0; kc < 2; kc++)
#pragma unroll
            for (int kb2 = 0; kb2 < 2; kb2++)
#pragma unroll
                for (int qb = 0; qb < 2; qb++)
                    sacc[kb2][qb] = __builtin_amdgcn_mfma_f32_16x16x32_bf16(
                        kf[kc][kb2], qf[qb][kc], sacc[kb2][qb], 0, 0, 0);
        __builtin_amdgcn_s_setprio(0);

        // P^T = exp2(S^T); causal mask on diagonal tile; pack via cvt_pk into
        // PV A-frags: elem e = kb2*4+rg <-> key khalf*32 + kb2*16 + quad*4 + rg
        union { bf16x8 v; u32 w[4]; } pk[2];
        if (j == qt) {
            const int key0 = khalf * 32 + quad * 4;
#pragma unroll
            for (int qb = 0; qb < 2; qb++) {
                const int gq = qhalf * 32 + qb * 16 + l15;
#pragma unroll
                for (int kb2 = 0; kb2 < 2; kb2++) {
                    float e0 = __builtin_amdgcn_exp2f(sacc[kb2][qb][0]);
                    float e1 = __builtin_amdgcn_exp2f(sacc[kb2][qb][1]);
                    float e2 = __builtin_amdgcn_exp2f(sacc[kb2][qb][2]);
                    float e3 = __builtin_amdgcn_exp2f(sacc[kb2][qb][3]);
                    int kbase = key0 + kb2 * 16;
                    if (kbase + 0 > gq) e0 = 0.f;
                    if (kbase + 1 > gq) e1 = 0.f;
                    if (kbase + 2 > gq) e2 = 0.f;
                    if (kbase + 3 > gq) e3 = 0.f;
                    pk[qb].w[kb2 * 2 + 0] = cvtpk_bf16(e0, e1);
                    pk[qb].w[kb2 * 2 + 1] = cvtpk_bf16(e2, e3);
                }
            }
        } else {
#pragma unroll
            for (int qb = 0; qb < 2; qb++)
#pragma unroll
                for (int kb2 = 0; kb2 < 2; kb2++) {
                    float e0 = __builtin_amdgcn_exp2f(sacc[kb2][qb][0]);
                    float e1 = __builtin_amdgcn_exp2f(sacc[kb2][qb][1]);
                    float e2 = __builtin_amdgcn_exp2f(sacc[kb2][qb][2]);
                    float e3 = __builtin_amdgcn_exp2f(sacc[kb2][qb][3]);
                    pk[qb].w[kb2 * 2 + 0] = cvtpk_bf16(e0, e1);
                    pk[qb].w[kb2 * 2 + 1] = cvtpk_bf16(e2, e3);
                }
        }

        // V fragments (read after sacc dies -- keeps the register peak low)
        const u16* Vc = Vl[cur];
        bf16x8 vf[4];
#pragma unroll
        for (int dt = 0; dt < 4; dt++) {
            int d = dt * 16 + l15;
            vf[dt] = *(const bf16x8*)(Vc + d * 64 + ((khalf * 4 + quad + d) & 7) * 8);
        }

        // O_partial += P . V (8 MFMA) ; row-sums += P . ones (2 MFMA)
        __builtin_amdgcn_s_setprio(1);
#pragma unroll
        for (int dt = 0; dt < 4; dt++)
#pragma unroll
            for (int qb = 0; qb < 2; qb++)
                o_acc[qb][dt] = __builtin_amdgcn_mfma_f32_16x16x32_bf16(
                    pk[qb].v, vf[dt], o_acc[qb][dt], 0, 0, 0);
        lsacc[0] = __builtin_amdgcn_mfma_f32_16x16x32_bf16(pk[0].v, ones, lsacc[0], 0, 0, 0);
        lsacc[1] = __builtin_amdgcn_mfma_f32_16x16x32_bf16(pk[1].v, ones, lsacc[1], 0, 0, 0);
        __builtin_amdgcn_s_setprio(0);
    };

    // pair loop: one wait+barrier per 2 tiles
    for (int j = 0; j <= qtHi; j += 2) {
        WAIT_VM(0);                                // retire tiles {j, j+1}
        __builtin_amdgcn_s_barrier();              // all waves' pair in LDS
        if (j + 2 <= qtHi) stage(j + 2, (j + 2) & 3);  // into free ring slots
        if (j + 3 <= qtHi) stage(j + 3, (j + 3) & 3);

        if (j <= qt) compute(j);                   // wave-uniform guards
        if (j + 1 <= qtHi && j + 1 <= qt) compute(j + 1);
    }

    // ---- epilogue: khalf pair-reduce via LDS, normalize, store ----
    // lsacc[qb][rg] = partial row-sum for q = qrow_base + qb*16 + quad*4 + rg
    // (identical across l15) -- exactly o_acc's row indexing.
    __syncthreads();                               // main-loop LDS use complete
    const int r = wave >> 1;                       // pair region 0..3
    float* xch = ((r & 2) ? (float*)&Vl[0][0] : (float*)&Kl[0][0]) + (r & 1) * 2560;
    floatx4* xv = (floatx4*)xch;                   // [plane 0..9][lane] 16B, conflict-free
    if (khalf == 0) {
#pragma unroll
        for (int qb = 0; qb < 2; qb++) {
#pragma unroll
            for (int dt = 0; dt < 4; dt++) xv[(qb * 4 + dt) * 64 + lane] = o_acc[qb][dt];
            xv[(8 + qb) * 64 + lane] = lsacc[qb];
        }
    }
    __syncthreads();
    if (khalf == 1) {
        float* op = out + (size_t)bh * T_SEQ * HDIM;
#pragma unroll
        for (int qb = 0; qb < 2; qb++) {
#pragma unroll
            for (int dt = 0; dt < 4; dt++) o_acc[qb][dt] += xv[(qb * 4 + dt) * 64 + lane];
            lsacc[qb] += xv[(8 + qb) * 64 + lane];
#pragma unroll
            for (int rg = 0; rg < 4; rg++) {
                float inv = 1.0f / lsacc[qb][rg];
                size_t row = (size_t)(qrow_base + qb * 16 + quad * 4 + rg) * HDIM;
#pragma unroll
                for (int dt = 0; dt < 4; dt++)
                    op[row + dt * 16 + l15] = o_acc[qb][dt][rg] * inv;
            }
        }
    }
}

extern "C" void kernel_launch(void* const* d_in, const int* in_sizes, int n_in,
                              void* d_out, int out_size, void* d_ws, size_t ws_size,
                              hipStream_t stream) {
    const float* q = (const float*)d_in[0];
    const float* k = (const float*)d_in[1];
    const float* v = (const float*)d_in[2];
    float* out = (float*)d_out;

    u16* kb = (u16*)d_ws;                               // 8 MB bf16 K
    u16* vt = kb + (size_t)NBH * T_SEQ * HDIM;          // 8 MB bf16 V^T (permuted)

    prep<<<dim3(T_SEQ / 32, NBH), 256, 0, stream>>>(k, v, kb, vt);
    fattn<<<dim3(512), 512, 0, stream>>>(q, kb, vt, out);
}